// Round 1
// baseline (484.041 us; speedup 1.0000x reference)
//
#include <hip/hip_runtime.h>

// Problem constants
#define B_ 4
#define N_ 4096
#define D_ 256
#define M_ (B_*N_)   // 16384

typedef _Float16 f16;
typedef _Float16 f16x8 __attribute__((ext_vector_type(8)));
typedef float    f32x4 __attribute__((ext_vector_type(4)));

// workspace layout (bytes)
#define QH_OFF   0u
#define KH_OFF   8388608u      // Qh: 16384*256*2
#define VT_OFF   16777216u     // Kh: same
#define WFC_OFF  25165824u     // Vt: [4][256][4096] f16
#define OP_OFF   25296896u     // Wfch: 256*256*2 = 131072
#define ML_OFF   58851328u     // Opart: 2*16384*256*4 = 33554432
// Ml: 2*16384*2*4 = 262144  -> total 59113472 bytes (~56.4 MB)

// ---------------------------------------------------------------------------
// Kernel 1: fused QKV projection, fp32 compute (accuracy for logits), fp16 out.
// q[m][e] = sum_d x[m][d]*W[e][d] + b[e]   (x @ W^T + b)
// z==2 (V) is stored TRANSPOSED: Vt[b][e][n]  so attention V B-frags are
// contiguous-in-key b128 LDS reads.
// ---------------------------------------------------------------------------
__global__ __launch_bounds__(256) void proj_kernel(
    const float* __restrict__ x,
    const float* __restrict__ Wq, const float* __restrict__ bq,
    const float* __restrict__ Wk, const float* __restrict__ bk,
    const float* __restrict__ Wv, const float* __restrict__ bv,
    f16* __restrict__ Qh, f16* __restrict__ Kh, f16* __restrict__ Vt)
{
    const int bz = blockIdx.z;
    const float* W    = (bz == 0) ? Wq : (bz == 1) ? Wk : Wv;
    const float* bias = (bz == 0) ? bq : (bz == 1) ? bk : bv;

    // transposed tiles (k-major) so the inner loop reads float4 (ds_read_b128)
    __shared__ float XsT[32][68];   // [kk][row], pad 68 -> 272B row stride
    __shared__ float WsT[32][68];   // [kk][col]

    const int tid  = threadIdx.x;
    const int row0 = blockIdx.x * 64;
    const int col0 = blockIdx.y * 64;
    const int ti = tid >> 4;        // 0..15 -> 4 rows each
    const int tj = tid & 15;        // 0..15 -> 4 cols each

    float acc[4][4] = {};

    for (int k0 = 0; k0 < 256; k0 += 32) {
        __syncthreads();
        #pragma unroll
        for (int i = 0; i < 2; i++) {
            int idx = tid + i * 256;          // 0..511
            int r = idx >> 3, c4 = idx & 7;   // 64 rows x 8 float4
            float4 v = *(const float4*)(x + (size_t)(row0 + r) * 256 + k0 + c4 * 4);
            XsT[c4*4+0][r] = v.x; XsT[c4*4+1][r] = v.y;
            XsT[c4*4+2][r] = v.z; XsT[c4*4+3][r] = v.w;
            float4 u = *(const float4*)(W + (size_t)(col0 + r) * 256 + k0 + c4 * 4);
            WsT[c4*4+0][r] = u.x; WsT[c4*4+1][r] = u.y;
            WsT[c4*4+2][r] = u.z; WsT[c4*4+3][r] = u.w;
        }
        __syncthreads();
        #pragma unroll
        for (int kk = 0; kk < 32; kk++) {
            float4 a = *(const float4*)&XsT[kk][ti*4];
            float4 bvec = *(const float4*)&WsT[kk][tj*4];
            float av[4] = {a.x, a.y, a.z, a.w};
            float bv4[4] = {bvec.x, bvec.y, bvec.z, bvec.w};
            #pragma unroll
            for (int r = 0; r < 4; r++)
                #pragma unroll
                for (int c = 0; c < 4; c++)
                    acc[r][c] = fmaf(av[r], bv4[c], acc[r][c]);
        }
    }

    if (bz < 2) {
        f16* outh = (bz == 0) ? Qh : Kh;
        #pragma unroll
        for (int r = 0; r < 4; r++) {
            union { ushort4 u4; f16 h[4]; } pk;
            #pragma unroll
            for (int c = 0; c < 4; c++)
                pk.h[c] = (f16)(acc[r][c] + bias[col0 + tj*4 + c]);
            *(ushort4*)(outh + (size_t)(row0 + ti*4 + r) * 256 + col0 + tj*4) = pk.u4;
        }
    } else {
        const int bb = row0 >> 12;              // batch (64 | 4096 so uniform)
        const int n0 = (row0 & 4095) + ti*4;
        #pragma unroll
        for (int c = 0; c < 4; c++) {
            int e = col0 + tj*4 + c;
            float bv_ = bias[e];
            #pragma unroll
            for (int r = 0; r < 4; r++)
                Vt[((size_t)bb*256 + e)*4096 + n0 + r] = (f16)(acc[r][c] + bv_);
        }
    }
}

// ---------------------------------------------------------------------------
// Kernel 2: Wfc -> fp16
// ---------------------------------------------------------------------------
__global__ __launch_bounds__(256) void cvt_wfc(const float* __restrict__ Wfc,
                                               f16* __restrict__ Wfch)
{
    int i = (blockIdx.x * 256 + threadIdx.x) * 4;
    float4 v = *(const float4*)(Wfc + i);
    union { ushort4 u4; f16 h[4]; } pk;
    pk.h[0] = (f16)v.x; pk.h[1] = (f16)v.y; pk.h[2] = (f16)v.z; pk.h[3] = (f16)v.w;
    *(ushort4*)(Wfch + i) = pk.u4;
}

// ---------------------------------------------------------------------------
// Kernel 3: flash attention, fp16 MFMA, split-K x2.
// grid 512: blk&7 -> (batch, k-half) so blk%8 XCD round-robin gives each XCD
// one 2MB K/V working set (L2-resident). blk>>3 -> q-tile of 64 rows.
// Block = 4 waves; wave w owns q rows qt*64 + w*16 (independent flash).
// TK=32 keys per iteration, 64 iterations over the 2048-key half.
// Writes UNNORMALIZED O plus (m, l) for the merge kernel.
// ---------------------------------------------------------------------------
__global__ __launch_bounds__(256) void attn_kernel(
    const f16* __restrict__ Qh, const f16* __restrict__ Kh,
    const f16* __restrict__ Vt,
    float* __restrict__ Opart, float* __restrict__ Ml)
{
    __shared__ f16 Ks[32][264];     // [key][d]  pad 264 -> 528B stride (16B mult)
    __shared__ f16 VsT[256][40];    // [d][key]  pad 40  -> 80B stride  (16B mult)
    __shared__ f16 Ps[4][16][40];   // per-wave P round-trip (C-layout -> A-layout)

    const int combo = blockIdx.x & 7;
    const int b  = combo >> 1;
    const int kh = combo & 1;
    const int qt = blockIdx.x >> 3;          // 0..63
    const int tid  = threadIdx.x;
    const int w    = tid >> 6;
    const int lane = tid & 63;
    const int l15  = lane & 15;
    const int q4   = lane >> 4;
    const int qrow = qt * 64 + w * 16;       // strip base row within batch

    // Q fragments resident in registers: A[m=l15][k=q4*8+j], 8 d-chunks of 32
    f16x8 qf[8];
    {
        const f16* qp = Qh + ((size_t)(b * 4096 + qrow + l15)) * 256 + q4 * 8;
        #pragma unroll
        for (int dc = 0; dc < 8; dc++)
            qf[dc] = *(const f16x8*)(qp + dc * 32);
    }

    f32x4 Oa[16];
    #pragma unroll
    for (int nt = 0; nt < 16; nt++) Oa[nt] = (f32x4){0.f, 0.f, 0.f, 0.f};
    float mo[4] = {-3e38f, -3e38f, -3e38f, -3e38f};
    float ls[4] = {0.f, 0.f, 0.f, 0.f};

    const int kbase = kh * 2048;
    for (int it = 0; it < 64; it++) {
        const int k0 = kbase + it * 32;
        __syncthreads();   // protect K/V LDS reuse from previous iteration
        // stage K tile: 32 keys x 256 d (16KB)
        #pragma unroll
        for (int i = 0; i < 4; i++) {
            int idx = tid + i * 256;
            int row = idx >> 5, c = idx & 31;
            *(f16x8*)&Ks[row][c*8] =
                *(const f16x8*)(Kh + ((size_t)(b*4096 + k0 + row))*256 + c*8);
        }
        // stage V^T tile: 256 d x 32 keys (16KB); thread t = one d-row
        {
            const f16* vp = Vt + ((size_t)(b*256 + tid))*4096 + k0;
            #pragma unroll
            for (int i = 0; i < 4; i++)
                *(f16x8*)&VsT[tid][i*8] = *(const f16x8*)(vp + i*8);
        }
        __syncthreads();

        // S = Q K^T : 16 q-rows x 32 keys, two 16x16 tiles, K=32 per mfma
        f32x4 s0 = {0.f,0.f,0.f,0.f}, s1 = {0.f,0.f,0.f,0.f};
        #pragma unroll
        for (int dc = 0; dc < 8; dc++) {
            f16x8 b0 = *(const f16x8*)&Ks[l15][dc*32 + q4*8];
            f16x8 b1 = *(const f16x8*)&Ks[16 + l15][dc*32 + q4*8];
            s0 = __builtin_amdgcn_mfma_f32_16x16x32_f16(qf[dc], b0, s0, 0, 0, 0);
            s1 = __builtin_amdgcn_mfma_f32_16x16x32_f16(qf[dc], b1, s1, 0, 0, 0);
        }

        // online softmax. lane holds rows q4*4+r, col l15 (s0) / 16+l15 (s1)
        float tm[4], al[4], p0[4], p1[4], rs[4];
        #pragma unroll
        for (int r = 0; r < 4; r++) tm[r] = fmaxf(s0[r], s1[r]);
        #pragma unroll
        for (int off = 1; off < 16; off <<= 1)
            #pragma unroll
            for (int r = 0; r < 4; r++)
                tm[r] = fmaxf(tm[r], __shfl_xor(tm[r], off));
        #pragma unroll
        for (int r = 0; r < 4; r++) {
            float mn = fmaxf(mo[r], tm[r]);
            al[r] = __expf(mo[r] - mn);
            p0[r] = __expf(s0[r] - mn);
            p1[r] = __expf(s1[r] - mn);
            mo[r] = mn;
            rs[r] = p0[r] + p1[r];
        }
        #pragma unroll
        for (int off = 1; off < 16; off <<= 1)
            #pragma unroll
            for (int r = 0; r < 4; r++)
                rs[r] += __shfl_xor(rs[r], off);
        #pragma unroll
        for (int r = 0; r < 4; r++) ls[r] = ls[r] * al[r] + rs[r];
        #pragma unroll
        for (int nt = 0; nt < 16; nt++)
            #pragma unroll
            for (int r = 0; r < 4; r++)
                Oa[nt][r] *= al[r];

        // P: C-layout -> LDS -> A-layout (wave-private; compiler inserts lgkmcnt)
        #pragma unroll
        for (int r = 0; r < 4; r++) {
            Ps[w][q4*4+r][l15]      = (f16)p0[r];
            Ps[w][q4*4+r][16 + l15] = (f16)p1[r];
        }
        f16x8 ap = *(const f16x8*)&Ps[w][l15][q4*8];

        // O += P V : 16 output d-tiles, K=32 (one mfma each)
        #pragma unroll
        for (int nt = 0; nt < 16; nt++) {
            f16x8 bv = *(const f16x8*)&VsT[nt*16 + l15][q4*8];
            Oa[nt] = __builtin_amdgcn_mfma_f32_16x16x32_f16(ap, bv, Oa[nt], 0, 0, 0);
        }
    }

    // store partial O (unnormalized) and (m, l)
    float* op = Opart + ((size_t)kh * M_ + b*4096 + qrow) * 256;
    #pragma unroll
    for (int nt = 0; nt < 16; nt++)
        #pragma unroll
        for (int r = 0; r < 4; r++)
            op[(size_t)(q4*4 + r) * 256 + nt*16 + l15] = Oa[nt][r];
    if (l15 == 0) {
        #pragma unroll
        for (int r = 0; r < 4; r++) {
            size_t mrow = (size_t)kh * M_ + b*4096 + qrow + q4*4 + r;
            Ml[mrow*2]     = mo[r];
            Ml[mrow*2 + 1] = ls[r];
        }
    }
}

// ---------------------------------------------------------------------------
// Kernel 4: merge the two k-halves + FC (fp16 MFMA) + bias.
// O loaded straight in A-fragment layout (rows = l15), so no LDS needed.
// ---------------------------------------------------------------------------
__global__ __launch_bounds__(256) void merge_fc_kernel(
    const float* __restrict__ Opart, const float* __restrict__ Ml,
    const f16* __restrict__ Wfch, const float* __restrict__ bfc,
    float* __restrict__ out)
{
    const int tid  = threadIdx.x;
    const int w    = tid >> 6;
    const int lane = tid & 63;
    const int l15  = lane & 15;
    const int q4   = lane >> 4;
    const int m0   = blockIdx.x * 64 + w * 16;

    const int rowA = m0 + l15;
    float m1 = Ml[(size_t)rowA*2],            l1 = Ml[(size_t)rowA*2 + 1];
    float m2 = Ml[((size_t)M_ + rowA)*2],     l2 = Ml[((size_t)M_ + rowA)*2 + 1];
    float mm = fmaxf(m1, m2);
    float w1 = __expf(m1 - mm), w2 = __expf(m2 - mm);
    float inv = 1.0f / (w1*l1 + w2*l2);
    float c1 = w1 * inv, c2 = w2 * inv;

    f16x8 af[8];
    const float* o1 = Opart + (size_t)rowA * 256 + q4*8;
    const float* o2 = Opart + ((size_t)M_ + rowA) * 256 + q4*8;
    #pragma unroll
    for (int dc = 0; dc < 8; dc++) {
        float4 a0 = *(const float4*)(o1 + dc*32);
        float4 a1 = *(const float4*)(o1 + dc*32 + 4);
        float4 b0 = *(const float4*)(o2 + dc*32);
        float4 b1 = *(const float4*)(o2 + dc*32 + 4);
        f16x8 v;
        v[0] = (f16)(c1*a0.x + c2*b0.x); v[1] = (f16)(c1*a0.y + c2*b0.y);
        v[2] = (f16)(c1*a0.z + c2*b0.z); v[3] = (f16)(c1*a0.w + c2*b0.w);
        v[4] = (f16)(c1*a1.x + c2*b1.x); v[5] = (f16)(c1*a1.y + c2*b1.y);
        v[6] = (f16)(c1*a1.z + c2*b1.z); v[7] = (f16)(c1*a1.w + c2*b1.w);
        af[dc] = v;
    }

    f32x4 acc[16];
    #pragma unroll
    for (int nt = 0; nt < 16; nt++) acc[nt] = (f32x4){0.f, 0.f, 0.f, 0.f};
    #pragma unroll
    for (int dc = 0; dc < 8; dc++) {
        #pragma unroll
        for (int nt = 0; nt < 16; nt++) {
            f16x8 bf = *(const f16x8*)(Wfch + (size_t)(nt*16 + l15)*256 + dc*32 + q4*8);
            acc[nt] = __builtin_amdgcn_mfma_f32_16x16x32_f16(af[dc], bf, acc[nt], 0, 0, 0);
        }
    }
    #pragma unroll
    for (int nt = 0; nt < 16; nt++) {
        float bias = bfc[nt*16 + l15];
        #pragma unroll
        for (int r = 0; r < 4; r++)
            out[(size_t)(m0 + q4*4 + r) * 256 + nt*16 + l15] = acc[nt][r] + bias;
    }
}

// ---------------------------------------------------------------------------
extern "C" void kernel_launch(void* const* d_in, const int* in_sizes, int n_in,
                              void* d_out, int out_size, void* d_ws, size_t ws_size,
                              hipStream_t stream)
{
    const float* x   = (const float*)d_in[0];
    const float* Wq  = (const float*)d_in[1];
    const float* bq  = (const float*)d_in[2];
    const float* Wk  = (const float*)d_in[3];
    const float* bk  = (const float*)d_in[4];
    const float* Wv  = (const float*)d_in[5];
    const float* bv  = (const float*)d_in[6];
    const float* Wfc = (const float*)d_in[7];
    const float* bfc = (const float*)d_in[8];
    float* out = (float*)d_out;

    char* ws = (char*)d_ws;
    f16*   Qh    = (f16*)(ws + QH_OFF);
    f16*   Kh    = (f16*)(ws + KH_OFF);
    f16*   Vt    = (f16*)(ws + VT_OFF);
    f16*   Wfch  = (f16*)(ws + WFC_OFF);
    float* Opart = (float*)(ws + OP_OFF);
    float* Ml    = (float*)(ws + ML_OFF);

    proj_kernel<<<dim3(256, 4, 3), 256, 0, stream>>>(x, Wq, bq, Wk, bk, Wv, bv, Qh, Kh, Vt);
    cvt_wfc<<<64, 256, 0, stream>>>(Wfc, Wfch);
    attn_kernel<<<512, 256, 0, stream>>>(Qh, Kh, Vt, Opart, Ml);
    merge_fc_kernel<<<256, 256, 0, stream>>>(Opart, Ml, Wfch, bfc, out);
}

// Round 2
// 377.505 us; speedup vs baseline: 1.2822x; 1.2822x over previous
//
#include <hip/hip_runtime.h>

// Problem constants
#define B_ 4
#define N_ 4096
#define D_ 256
#define M_ (B_*N_)   // 16384

typedef _Float16 f16;
typedef _Float16 f16x8 __attribute__((ext_vector_type(8)));
typedef float    f32x4 __attribute__((ext_vector_type(4)));

// workspace layout (bytes)
#define QH_OFF   0u
#define KH_OFF   8388608u      // Qh: 16384*256*2
#define VT_OFF   16777216u     // Kh: same
#define WFC_OFF  25165824u     // Vt: [4][256][4096] f16
#define OP_OFF   25296896u     // Wfch: 256*256*2 = 131072
#define ML_OFF   58851328u     // Opart: f16 [4][16384][256] = 33554432
// Ml: f32 [4][16384][2] = 524288 -> total 59375616 (~56.6 MB)

// ---------------------------------------------------------------------------
// Kernel 1: fused QKV projection, fp32 compute (accuracy for logits), fp16 out.
// (unchanged from R1 — passed; optimize in a later round)
// ---------------------------------------------------------------------------
__global__ __launch_bounds__(256) void proj_kernel(
    const float* __restrict__ x,
    const float* __restrict__ Wq, const float* __restrict__ bq,
    const float* __restrict__ Wk, const float* __restrict__ bk,
    const float* __restrict__ Wv, const float* __restrict__ bv,
    f16* __restrict__ Qh, f16* __restrict__ Kh, f16* __restrict__ Vt)
{
    const int bz = blockIdx.z;
    const float* W    = (bz == 0) ? Wq : (bz == 1) ? Wk : Wv;
    const float* bias = (bz == 0) ? bq : (bz == 1) ? bk : bv;

    __shared__ float XsT[32][68];
    __shared__ float WsT[32][68];

    const int tid  = threadIdx.x;
    const int row0 = blockIdx.x * 64;
    const int col0 = blockIdx.y * 64;
    const int ti = tid >> 4;
    const int tj = tid & 15;

    float acc[4][4] = {};

    for (int k0 = 0; k0 < 256; k0 += 32) {
        __syncthreads();
        #pragma unroll
        for (int i = 0; i < 2; i++) {
            int idx = tid + i * 256;
            int r = idx >> 3, c4 = idx & 7;
            float4 v = *(const float4*)(x + (size_t)(row0 + r) * 256 + k0 + c4 * 4);
            XsT[c4*4+0][r] = v.x; XsT[c4*4+1][r] = v.y;
            XsT[c4*4+2][r] = v.z; XsT[c4*4+3][r] = v.w;
            float4 u = *(const float4*)(W + (size_t)(col0 + r) * 256 + k0 + c4 * 4);
            WsT[c4*4+0][r] = u.x; WsT[c4*4+1][r] = u.y;
            WsT[c4*4+2][r] = u.z; WsT[c4*4+3][r] = u.w;
        }
        __syncthreads();
        #pragma unroll
        for (int kk = 0; kk < 32; kk++) {
            float4 a = *(const float4*)&XsT[kk][ti*4];
            float4 bvec = *(const float4*)&WsT[kk][tj*4];
            float av[4] = {a.x, a.y, a.z, a.w};
            float bv4[4] = {bvec.x, bvec.y, bvec.z, bvec.w};
            #pragma unroll
            for (int r = 0; r < 4; r++)
                #pragma unroll
                for (int c = 0; c < 4; c++)
                    acc[r][c] = fmaf(av[r], bv4[c], acc[r][c]);
        }
    }

    if (bz < 2) {
        f16* outh = (bz == 0) ? Qh : Kh;
        #pragma unroll
        for (int r = 0; r < 4; r++) {
            union { ushort4 u4; f16 h[4]; } pk;
            #pragma unroll
            for (int c = 0; c < 4; c++)
                pk.h[c] = (f16)(acc[r][c] + bias[col0 + tj*4 + c]);
            *(ushort4*)(outh + (size_t)(row0 + ti*4 + r) * 256 + col0 + tj*4) = pk.u4;
        }
    } else {
        const int bb = row0 >> 12;
        const int n0 = (row0 & 4095) + ti*4;
        #pragma unroll
        for (int c = 0; c < 4; c++) {
            int e = col0 + tj*4 + c;
            float bv_ = bias[e];
            #pragma unroll
            for (int r = 0; r < 4; r++)
                Vt[((size_t)bb*256 + e)*4096 + n0 + r] = (f16)(acc[r][c] + bv_);
        }
    }
}

// ---------------------------------------------------------------------------
// Kernel 2: Wfc -> fp16
// ---------------------------------------------------------------------------
__global__ __launch_bounds__(256) void cvt_wfc(const float* __restrict__ Wfc,
                                               f16* __restrict__ Wfch)
{
    int i = (blockIdx.x * 256 + threadIdx.x) * 4;
    float4 v = *(const float4*)(Wfc + i);
    union { ushort4 u4; f16 h[4]; } pk;
    pk.h[0] = (f16)v.x; pk.h[1] = (f16)v.y; pk.h[2] = (f16)v.z; pk.h[3] = (f16)v.w;
    *(ushort4*)(Wfch + i) = pk.u4;
}

// ---------------------------------------------------------------------------
// Kernel 3: flash attention, fp16 MFMA, split-K x4.
// R2 restructure: wave owns 32 q-rows as 2x16 subtiles; every K/V B-fragment
// read from LDS is reused by BOTH subtiles -> LDS bytes per q*k pair halved
// vs R1 (the measured bottleneck). 512 blocks (2/CU). Partial O stored
// NORMALIZED in f16 (per-row 1/l applied) + (m,l) f32 for the merge.
// blockIdx&15 -> (batch, k-quarter): 16 combos over 8 XCDs -> 2MB K/V
// working set per XCD, L2-resident.
// ---------------------------------------------------------------------------
__global__ __launch_bounds__(256, 2) void attn_kernel(
    const f16* __restrict__ Qh, const f16* __restrict__ Kh,
    const f16* __restrict__ Vt,
    f16* __restrict__ Opart, float* __restrict__ Ml)
{
    __shared__ f16 Ks[32][264];     // [key][d]   528B row = 33*16B (odd -> 2-way max)
    __shared__ f16 VsT[256][40];    // [d][key]   80B row = 5*16B
    __shared__ f16 Ps[4][32][40];   // per-wave P round-trip (C-layout -> A-layout)

    const int combo = blockIdx.x & 15;
    const int b   = combo >> 2;
    const int sp  = combo & 3;               // k-quarter: keys sp*1024 .. +1023
    const int qt  = blockIdx.x >> 4;         // 0..31
    const int tid  = threadIdx.x;
    const int w    = tid >> 6;
    const int lane = tid & 63;
    const int l15  = lane & 15;
    const int q4   = lane >> 4;
    const int qbase = qt * 128 + w * 32;     // row within batch

    // Q fragments resident: qf[s][dc] covers rows qbase+s*16, A[m=l15][k=q4*8+j]
    f16x8 qf[2][8];
    #pragma unroll
    for (int s = 0; s < 2; s++) {
        const f16* qp = Qh + ((size_t)(b*4096 + qbase + s*16 + l15)) * 256 + q4*8;
        #pragma unroll
        for (int dc = 0; dc < 8; dc++)
            qf[s][dc] = *(const f16x8*)(qp + dc*32);
    }

    f32x4 Oa[2][16];
    #pragma unroll
    for (int s = 0; s < 2; s++)
        #pragma unroll
        for (int nt = 0; nt < 16; nt++) Oa[s][nt] = (f32x4){0.f,0.f,0.f,0.f};
    float mo[2][4] = {{-3e38f,-3e38f,-3e38f,-3e38f},{-3e38f,-3e38f,-3e38f,-3e38f}};
    float ls[2][4] = {};

    const f16* kp = Kh + ((size_t)(b*4096 + sp*1024)) * 256;
    const f16* vp = Vt + ((size_t)b*256) * 4096 + sp*1024;
    const int vno = (tid & 3) * 8;           // V staging: 4 lanes cover 32 keys
    const int vd0 = tid >> 2;                // d rows 0..63 (+64 per rep)

    for (int it = 0; it < 32; it++) {
        __syncthreads();                     // prev iter done reading Ks/VsT
        // stage K: 32 keys x 256 d, coalesced 512B per 32 lanes
        #pragma unroll
        for (int i = 0; i < 4; i++) {
            int idx = tid + i*256;
            int row = idx >> 5, c = idx & 31;
            *(f16x8*)&Ks[row][c*8] = *(const f16x8*)(kp + (size_t)row*256 + c*8);
        }
        // stage V^T: 256 d x 32 keys; 4-lane 64B segments (cache-line coalesced)
        #pragma unroll
        for (int i = 0; i < 4; i++) {
            int d = vd0 + i*64;
            *(f16x8*)&VsT[d][vno] = *(const f16x8*)(vp + (size_t)d*4096 + vno);
        }
        kp += 32*256; vp += 32;
        __syncthreads();

        // S = Q K^T : 32 q-rows x 32 keys; each K B-frag reused by both subtiles
        f32x4 sa[2][2] = {{{0.f,0.f,0.f,0.f},{0.f,0.f,0.f,0.f}},
                          {{0.f,0.f,0.f,0.f},{0.f,0.f,0.f,0.f}}};
        #pragma unroll
        for (int dc = 0; dc < 8; dc++) {
            f16x8 b0 = *(const f16x8*)&Ks[l15][dc*32 + q4*8];
            f16x8 b1 = *(const f16x8*)&Ks[16 + l15][dc*32 + q4*8];
            sa[0][0] = __builtin_amdgcn_mfma_f32_16x16x32_f16(qf[0][dc], b0, sa[0][0], 0,0,0);
            sa[0][1] = __builtin_amdgcn_mfma_f32_16x16x32_f16(qf[0][dc], b1, sa[0][1], 0,0,0);
            sa[1][0] = __builtin_amdgcn_mfma_f32_16x16x32_f16(qf[1][dc], b0, sa[1][0], 0,0,0);
            sa[1][1] = __builtin_amdgcn_mfma_f32_16x16x32_f16(qf[1][dc], b1, sa[1][1], 0,0,0);
        }

        // online softmax per subtile (rows q4*4+r, cols l15 / 16+l15)
        #pragma unroll
        for (int s = 0; s < 2; s++) {
            float tm[4], al[4], rs[4];
            #pragma unroll
            for (int r = 0; r < 4; r++) tm[r] = fmaxf(sa[s][0][r], sa[s][1][r]);
            #pragma unroll
            for (int off = 1; off < 16; off <<= 1)
                #pragma unroll
                for (int r = 0; r < 4; r++)
                    tm[r] = fmaxf(tm[r], __shfl_xor(tm[r], off));
            #pragma unroll
            for (int r = 0; r < 4; r++) {
                float mn = fmaxf(mo[s][r], tm[r]);
                al[r] = __expf(mo[s][r] - mn);
                float p0 = __expf(sa[s][0][r] - mn);
                float p1 = __expf(sa[s][1][r] - mn);
                mo[s][r] = mn;
                rs[r] = p0 + p1;
                Ps[w][s*16 + q4*4 + r][l15]      = (f16)p0;
                Ps[w][s*16 + q4*4 + r][16 + l15] = (f16)p1;
            }
            #pragma unroll
            for (int off = 1; off < 16; off <<= 1)
                #pragma unroll
                for (int r = 0; r < 4; r++)
                    rs[r] += __shfl_xor(rs[r], off);
            #pragma unroll
            for (int r = 0; r < 4; r++) ls[s][r] = ls[s][r] * al[r] + rs[r];
            // lazy rescale: skip the 64 muls when max unchanged (common here:
            // unscaled logits have huge early maxima)
            bool nz = (al[0]!=1.f) | (al[1]!=1.f) | (al[2]!=1.f) | (al[3]!=1.f);
            if (__any(nz)) {
                #pragma unroll
                for (int nt = 0; nt < 16; nt++)
                    #pragma unroll
                    for (int r = 0; r < 4; r++)
                        Oa[s][nt][r] *= al[r];
            }
        }

        // P back as A-frags (wave-private; compiler inserts lgkmcnt)
        f16x8 ap0 = *(const f16x8*)&Ps[w][l15][q4*8];
        f16x8 ap1 = *(const f16x8*)&Ps[w][16 + l15][q4*8];

        // O += P V : each V B-frag reused by both subtiles
        #pragma unroll
        for (int nt = 0; nt < 16; nt++) {
            f16x8 bv = *(const f16x8*)&VsT[nt*16 + l15][q4*8];
            Oa[0][nt] = __builtin_amdgcn_mfma_f32_16x16x32_f16(ap0, bv, Oa[0][nt], 0,0,0);
            Oa[1][nt] = __builtin_amdgcn_mfma_f32_16x16x32_f16(ap1, bv, Oa[1][nt], 0,0,0);
        }
    }

    // epilogue: store NORMALIZED partial O (f16) + (m, l)
    #pragma unroll
    for (int s = 0; s < 2; s++) {
        float inv[4];
        #pragma unroll
        for (int r = 0; r < 4; r++) inv[r] = 1.0f / ls[s][r];
        f16* op = Opart + ((size_t)sp*M_ + b*4096 + qbase + s*16) * 256;
        #pragma unroll
        for (int nt = 0; nt < 16; nt++)
            #pragma unroll
            for (int r = 0; r < 4; r++)
                op[(size_t)(q4*4 + r) * 256 + nt*16 + l15] = (f16)(Oa[s][nt][r] * inv[r]);
        if (l15 == 0) {
            #pragma unroll
            for (int r = 0; r < 4; r++) {
                size_t mrow = (size_t)sp*M_ + b*4096 + qbase + s*16 + q4*4 + r;
                Ml[mrow*2]     = mo[s][r];
                Ml[mrow*2 + 1] = ls[s][r];
            }
        }
    }
}

// ---------------------------------------------------------------------------
// Kernel 4: merge 4 normalized k-quarter partials + FC (fp16 MFMA) + bias.
// weight_p = exp(m_p - m)*l_p / sum_p exp(m_p - m)*l_p
// ---------------------------------------------------------------------------
__global__ __launch_bounds__(256) void merge_fc_kernel(
    const f16* __restrict__ Opart, const float* __restrict__ Ml,
    const f16* __restrict__ Wfch, const float* __restrict__ bfc,
    float* __restrict__ out)
{
    const int tid  = threadIdx.x;
    const int w    = tid >> 6;
    const int lane = tid & 63;
    const int l15  = lane & 15;
    const int q4   = lane >> 4;
    const int m0   = blockIdx.x * 64 + w * 16;

    const int rowA = m0 + l15;
    float mv[4], lv[4];
    #pragma unroll
    for (int p = 0; p < 4; p++) {
        mv[p] = Ml[((size_t)p*M_ + rowA)*2];
        lv[p] = Ml[((size_t)p*M_ + rowA)*2 + 1];
    }
    float mm = fmaxf(fmaxf(mv[0], mv[1]), fmaxf(mv[2], mv[3]));
    float cw[4], den = 0.f;
    #pragma unroll
    for (int p = 0; p < 4; p++) { cw[p] = __expf(mv[p] - mm) * lv[p]; den += cw[p]; }
    float inv = 1.0f / den;
    #pragma unroll
    for (int p = 0; p < 4; p++) cw[p] *= inv;

    f16x8 af[8];
    #pragma unroll
    for (int dc = 0; dc < 8; dc++) {
        float v[8] = {};
        #pragma unroll
        for (int p = 0; p < 4; p++) {
            f16x8 o = *(const f16x8*)(Opart + ((size_t)p*M_ + rowA)*256 + q4*8 + dc*32);
            #pragma unroll
            for (int j = 0; j < 8; j++) v[j] += cw[p] * (float)o[j];
        }
        f16x8 h;
        #pragma unroll
        for (int j = 0; j < 8; j++) h[j] = (f16)v[j];
        af[dc] = h;
    }

    f32x4 acc[16];
    #pragma unroll
    for (int nt = 0; nt < 16; nt++) acc[nt] = (f32x4){0.f,0.f,0.f,0.f};
    #pragma unroll
    for (int dc = 0; dc < 8; dc++) {
        #pragma unroll
        for (int nt = 0; nt < 16; nt++) {
            f16x8 bf = *(const f16x8*)(Wfch + (size_t)(nt*16 + l15)*256 + dc*32 + q4*8);
            acc[nt] = __builtin_amdgcn_mfma_f32_16x16x32_f16(af[dc], bf, acc[nt], 0,0,0);
        }
    }
    #pragma unroll
    for (int nt = 0; nt < 16; nt++) {
        float bias = bfc[nt*16 + l15];
        #pragma unroll
        for (int r = 0; r < 4; r++)
            out[(size_t)(m0 + q4*4 + r) * 256 + nt*16 + l15] = acc[nt][r] + bias;
    }
}

// ---------------------------------------------------------------------------
extern "C" void kernel_launch(void* const* d_in, const int* in_sizes, int n_in,
                              void* d_out, int out_size, void* d_ws, size_t ws_size,
                              hipStream_t stream)
{
    const float* x   = (const float*)d_in[0];
    const float* Wq  = (const float*)d_in[1];
    const float* bq  = (const float*)d_in[2];
    const float* Wk  = (const float*)d_in[3];
    const float* bk  = (const float*)d_in[4];
    const float* Wv  = (const float*)d_in[5];
    const float* bv  = (const float*)d_in[6];
    const float* Wfc = (const float*)d_in[7];
    const float* bfc = (const float*)d_in[8];
    float* out = (float*)d_out;

    char* ws = (char*)d_ws;
    f16*   Qh    = (f16*)(ws + QH_OFF);
    f16*   Kh    = (f16*)(ws + KH_OFF);
    f16*   Vt    = (f16*)(ws + VT_OFF);
    f16*   Wfch  = (f16*)(ws + WFC_OFF);
    f16*   Opart = (f16*)(ws + OP_OFF);
    float* Ml    = (float*)(ws + ML_OFF);

    proj_kernel<<<dim3(256, 4, 3), 256, 0, stream>>>(x, Wq, bq, Wk, bk, Wv, bv, Qh, Kh, Vt);
    cvt_wfc<<<64, 256, 0, stream>>>(Wfc, Wfch);
    attn_kernel<<<512, 256, 0, stream>>>(Qh, Kh, Vt, Opart, Ml);
    merge_fc_kernel<<<256, 256, 0, stream>>>(Opart, Ml, Wfch, bfc, out);
}